// Round 1
// 1494.717 us; speedup vs baseline: 1.2356x; 1.2356x over previous
//
#include <hip/hip_runtime.h>
#include <math.h>

namespace {

constexpr int IMS  = 84;
constexpr int NPIX = IMS * IMS;      // 7056
constexpr int KOBJ = 20;

// ---- workspace layout (float offsets), peak = 27448320 floats = 110 MB ----
constexpr size_t OFF_X    = 0;            // 512*512            -> 262144
constexpr size_t OFF_OT   = 262144;       // 512*40             -> 282624
constexpr size_t OFF_CT   = 282624;       // 512*2 (pad)        -> 283648
constexpr size_t OFF_WT2  = 283648;       // 512*64             -> 316416
constexpr size_t OFF_WT3  = 316416;       // 576*64             -> 353280
constexpr size_t OFF_M0   = 353280;       // 512*10584          -> 5772288
constexpr size_t OFF_R1   = 5772288;      // 512*24*42*42       -> 27448320
// H1/H2/FEAT alias into the R1 region (dead before upconv1 writes R1)
constexpr size_t OFF_H1   = OFF_R1;       // 512*32*400         -> 12325888
constexpr size_t OFF_H2   = 12325888;     // 512*64*81          -> 14980096
constexpr size_t OFF_FEAT = 14980096;     // 512*3136           -> 16585728
// decoder conv weights (transposed, 5184 floats each) reuse WT2/WT3 slots
// after conv2/conv3 are done with them.

// ---- generic weight transpose: w[oc][ckk] -> wt[ckk][oc] ----
__global__ void transpose_w(const float* __restrict__ w, float* __restrict__ wt,
                            int OC, int CKK) {
  int idx = blockIdx.x * 256 + threadIdx.x;
  if (idx < OC * CKK) {
    int oc = idx / CKK, ckk = idx % CKK;
    wt[ckk * OC + oc] = w[idx];
  }
}

// ---- conv1: [B,2,84,84] -> [B,32,20,20], k=8 s=4, relu. LDS 44.6 KB ----
__global__ __launch_bounds__(256) void conv1_k(
    const float* __restrict__ inp, const float* __restrict__ w,
    const float* __restrict__ bias, float* __restrict__ out) {
  __shared__ __align__(16) float sIn[NPIX];      // one channel at a time
  __shared__ __align__(16) float sW[128 * 32];   // [c][u][v][oc]
  const int b = blockIdx.x, t = threadIdx.x;
  for (int i = t; i < 4096; i += 256) {
    int oc = i >> 7, ckk = i & 127;
    sW[ckk * 32 + oc] = w[i];
  }
  const float* ip = inp + (size_t)b * 2 * NPIX;
  const int oc0 = (t & 7) * 4;
  const int pg  = t >> 3;
  int ibase[13];
#pragma unroll
  for (int k = 0; k < 13; k++) {
    int p = pg + 32 * k; if (p > 399) p = 399;
    ibase[k] = (p / 20) * 4 * 84 + (p % 20) * 4;
  }
  float acc[13][4];
#pragma unroll
  for (int k = 0; k < 13; k++) { acc[k][0]=0.f; acc[k][1]=0.f; acc[k][2]=0.f; acc[k][3]=0.f; }
  for (int c = 0; c < 2; c++) {
    __syncthreads();
    for (int i = t; i < NPIX; i += 256) sIn[i] = ip[c * NPIX + i];
    __syncthreads();
    for (int u = 0; u < 8; u++) {
#pragma unroll
      for (int v = 0; v < 8; v++) {
        const float4 wv = *(const float4*)&sW[((c * 8 + u) * 8 + v) * 32 + oc0];
        const int off = u * 84 + v;
#pragma unroll
        for (int k = 0; k < 13; k++) {
          float x = sIn[off + ibase[k]];
          acc[k][0] += x * wv.x; acc[k][1] += x * wv.y;
          acc[k][2] += x * wv.z; acc[k][3] += x * wv.w;
        }
      }
    }
  }
  float b0 = bias[oc0], b1 = bias[oc0+1], b2 = bias[oc0+2], b3 = bias[oc0+3];
  float* op = out + (size_t)b * 32 * 400;
#pragma unroll
  for (int k = 0; k < 13; k++) {
    int p = pg + 32 * k;
    if (p < 400) {
      op[(oc0+0)*400 + p] = fmaxf(acc[k][0] + b0, 0.f);
      op[(oc0+1)*400 + p] = fmaxf(acc[k][1] + b1, 0.f);
      op[(oc0+2)*400 + p] = fmaxf(acc[k][2] + b2, 0.f);
      op[(oc0+3)*400 + p] = fmaxf(acc[k][3] + b3, 0.f);
    }
  }
}

// ---- conv2: [B,32,20,20] -> [B,64,9,9], k=4 s=2, relu. LDS 51.2 KB ----
__global__ __launch_bounds__(256) void conv2_k(
    const float* __restrict__ in, const float* __restrict__ wt,
    const float* __restrict__ bias, float* __restrict__ out) {
  __shared__ float sIn[32 * 400];
  const int b = blockIdx.x, t = threadIdx.x;
  const float* ip = in + (size_t)b * 12800;
  for (int i = t; i < 12800; i += 256) sIn[i] = ip[i];
  __syncthreads();
  const int oc0 = (t & 7) * 8;
  const int pg  = t >> 3;
  int base[3];
#pragma unroll
  for (int k = 0; k < 3; k++) {
    int p = pg + 32 * k; if (p > 80) p = 80;
    base[k] = (p / 9) * 40 + (p % 9) * 2;
  }
  float acc[3][8];
#pragma unroll
  for (int k = 0; k < 3; k++)
#pragma unroll
    for (int o = 0; o < 8; o++) acc[k][o] = 0.f;
  for (int c = 0; c < 32; c++) {
#pragma unroll
    for (int u = 0; u < 4; u++)
#pragma unroll
      for (int v = 0; v < 4; v++) {
        const float* wp = wt + ((c * 4 + u) * 4 + v) * 64 + oc0;
        float4 wa = *(const float4*)wp;
        float4 wb = *(const float4*)(wp + 4);
        int off = c * 400 + u * 20 + v;
#pragma unroll
        for (int k = 0; k < 3; k++) {
          float x = sIn[off + base[k]];
          acc[k][0] += x*wa.x; acc[k][1] += x*wa.y; acc[k][2] += x*wa.z; acc[k][3] += x*wa.w;
          acc[k][4] += x*wb.x; acc[k][5] += x*wb.y; acc[k][6] += x*wb.z; acc[k][7] += x*wb.w;
        }
      }
  }
  float* op = out + (size_t)b * 5184;
#pragma unroll
  for (int k = 0; k < 3; k++) {
    int p = pg + 32 * k;
    if (p < 81) {
#pragma unroll
      for (int o = 0; o < 8; o++)
        op[(oc0+o)*81 + p] = fmaxf(acc[k][o] + bias[oc0+o], 0.f);
    }
  }
}

// ---- conv3: [B,64,9,9] -> feat [B,3136] (= [64][7][7] flat), k=3 s=1, relu ----
__global__ __launch_bounds__(256) void conv3_k(
    const float* __restrict__ in, const float* __restrict__ wt,
    const float* __restrict__ bias, float* __restrict__ out) {
  __shared__ float sIn[64 * 81];
  const int b = blockIdx.x, t = threadIdx.x;
  const float* ip = in + (size_t)b * 5184;
  for (int i = t; i < 5184; i += 256) sIn[i] = ip[i];
  __syncthreads();
  const int oc0 = (t & 7) * 8;
  const int pg  = t >> 3;
  int base[2];
#pragma unroll
  for (int k = 0; k < 2; k++) {
    int p = pg + 32 * k; if (p > 48) p = 48;
    base[k] = (p / 7) * 9 + (p % 7);
  }
  float acc[2][8];
#pragma unroll
  for (int k = 0; k < 2; k++)
#pragma unroll
    for (int o = 0; o < 8; o++) acc[k][o] = 0.f;
  for (int c = 0; c < 64; c++) {
#pragma unroll
    for (int u = 0; u < 3; u++)
#pragma unroll
      for (int v = 0; v < 3; v++) {
        const float* wp = wt + ((c * 3 + u) * 3 + v) * 64 + oc0;
        float4 wa = *(const float4*)wp;
        float4 wb = *(const float4*)(wp + 4);
        int off = c * 81 + u * 9 + v;
#pragma unroll
        for (int k = 0; k < 2; k++) {
          float x = sIn[off + base[k]];
          acc[k][0] += x*wa.x; acc[k][1] += x*wa.y; acc[k][2] += x*wa.z; acc[k][3] += x*wa.w;
          acc[k][4] += x*wb.x; acc[k][5] += x*wb.y; acc[k][6] += x*wb.z; acc[k][7] += x*wb.w;
        }
      }
  }
  float* op = out + (size_t)b * 3136;
#pragma unroll
  for (int k = 0; k < 2; k++) {
    int p = pg + 32 * k;
    if (p < 49) {
#pragma unroll
      for (int o = 0; o < 8; o++)
        op[(oc0+o)*49 + p] = fmaxf(acc[k][o] + bias[oc0+o], 0.f);
    }
  }
}

// ---- GEMM: C[M,N] = A[M,K] @ W[N,K]^T + bias, optional relu. M=512, K%16==0 ----
template<bool RELU>
__global__ __launch_bounds__(256) void gemm_k(
    const float* __restrict__ A, const float* __restrict__ Wm,
    const float* __restrict__ bias, float* __restrict__ C,
    int N, int K) {
  __shared__ __align__(16) float As[16][68];
  __shared__ __align__(16) float Ws[16][68];
  const int t = threadIdx.x;
  const int m0 = blockIdx.y * 64, n0 = blockIdx.x * 64;
  const int r  = t >> 2;
  const int kq = (t & 3) * 4;
  const int r0 = (t >> 4) * 4, c0 = (t & 15) * 4;
  float acc[4][4];
#pragma unroll
  for (int i = 0; i < 4; i++)
#pragma unroll
    for (int j = 0; j < 4; j++) acc[i][j] = 0.f;
  for (int k0 = 0; k0 < K; k0 += 16) {
    float4 a = *(const float4*)(A + (size_t)(m0 + r) * K + k0 + kq);
    int wrow = n0 + r;
    float4 wv = make_float4(0.f, 0.f, 0.f, 0.f);
    if (wrow < N) wv = *(const float4*)(Wm + (size_t)wrow * K + k0 + kq);
    __syncthreads();
    As[kq+0][r] = a.x; As[kq+1][r] = a.y; As[kq+2][r] = a.z; As[kq+3][r] = a.w;
    Ws[kq+0][r] = wv.x; Ws[kq+1][r] = wv.y; Ws[kq+2][r] = wv.z; Ws[kq+3][r] = wv.w;
    __syncthreads();
#pragma unroll
    for (int kk = 0; kk < 16; kk++) {
      float4 av = *(const float4*)&As[kk][r0];
      float4 bv = *(const float4*)&Ws[kk][c0];
      float ar[4] = {av.x, av.y, av.z, av.w};
      float br[4] = {bv.x, bv.y, bv.z, bv.w};
#pragma unroll
      for (int i = 0; i < 4; i++)
#pragma unroll
        for (int j = 0; j < 4; j++) acc[i][j] += ar[i] * br[j];
    }
  }
#pragma unroll
  for (int i = 0; i < 4; i++) {
    int row = m0 + r0 + i;
#pragma unroll
    for (int j = 0; j < 4; j++) {
      int col = n0 + c0 + j;
      if (col < N) {
        float v = acc[i][j] + bias[col];
        C[(size_t)row * N + col] = RELU ? fmaxf(v, 0.f) : v;
      }
    }
  }
}

// ---- upconv1: upsample 21->42 + residual 3x3 conv + relu.
//      One thread per output pixel, all 24 oc in registers; weights come in
//      pre-transposed [ic][ky][kx][oc] and are read with WAVE-UNIFORM indices
//      -> scalar (SGPR) loads, no LDS weight tile.  LDS 33 KB -> 4 blocks/CU.
__global__ __launch_bounds__(256, 4) void upconv1_k(
    const float* __restrict__ X, const float* __restrict__ wt,
    const float* __restrict__ bias, float* __restrict__ out) {
  constexpr int S_IN = 21, S_OUT = 42, TR = 6, UH = 8, UW = 44, NTILE = 7;
  __shared__ __align__(16) float sU[24 * UH * UW];   // 8448 floats = 33 KB
  const int b = blockIdx.x / NTILE;
  const int y0 = (blockIdx.x % NTILE) * TR;
  const int t = threadIdx.x;
  const float* xb = X + (size_t)b * 24 * S_IN * S_IN;
  const float sc = (float)(S_IN - 1) / (float)(S_OUT - 1);
  for (int i = t; i < 24 * UH * UW; i += 256) {
    int c = i / (UH * UW), rr = i % (UH * UW);
    int ry = rr / UW, cx = rr % UW;
    int y = y0 + ry - 1, x = cx - 1;
    float v = 0.f;
    if (y >= 0 && y < S_OUT && x >= 0 && x < S_OUT) {
      float py = y * sc, px = x * sc;
      int ly = (int)py; if (ly > S_IN - 2) ly = S_IN - 2;
      int lx = (int)px; if (lx > S_IN - 2) lx = S_IN - 2;
      float wy = py - (float)ly, wx = px - (float)lx;
      const float* xc = xb + c * S_IN * S_IN + ly * S_IN + lx;
      float v00 = xc[0], v01 = xc[1], v10 = xc[S_IN], v11 = xc[S_IN + 1];
      v = (1.f - wy) * ((1.f - wx) * v00 + wx * v01) +
          wy * ((1.f - wx) * v10 + wx * v11);
    }
    sU[i] = v;
  }
  __syncthreads();
  if (t < 252) {
    const int ry = t / 42, lx = t % 42;
    float acc[24];
#pragma unroll
    for (int o = 0; o < 24; o++) acc[o] = 0.f;
    for (int ic = 0; ic < 24; ic++) {
      const float* urow = &sU[(ic * UH + ry) * UW + lx];
      const float* wp = wt + ic * 216;   // [3][3][24], uniform -> s_load
#pragma unroll
      for (int ky = 0; ky < 3; ky++) {
        float x0v = urow[ky * UW + 0];
        float x1v = urow[ky * UW + 1];
        float x2v = urow[ky * UW + 2];
        const float* wk = wp + ky * 72;
#pragma unroll
        for (int o = 0; o < 24; o++)
          acc[o] += wk[o] * x0v + wk[24 + o] * x1v + wk[48 + o] * x2v;
      }
    }
    const int yy = y0 + ry;
#pragma unroll
    for (int o = 0; o < 24; o++) {
      float u = sU[(o * UH + ry + 1) * UW + lx + 1];
      out[(((size_t)b * 24 + o) * S_OUT + yy) * S_OUT + lx] =
          fmaxf(u + acc[o] + bias[o], 0.f);
    }
  }
}

// ---- fused: upsample 42->84 + residual conv + relu + 1x1 conv + sigmoid
//      + flow + bilinear warp.  One thread per pixel; all 24 channels live in
//      registers so the whole epilogue fuses in-register (no sOut staging).
//      Weights/heads read with uniform indices -> SGPR.  LDS 33 KB. ----
__global__ __launch_bounds__(256, 4) void upconv2_final_k(
    const float* __restrict__ R1, const float* __restrict__ inp,
    const float* __restrict__ wt, const float* __restrict__ bias,
    const float* __restrict__ c3w, const float* __restrict__ c3b,
    const float* __restrict__ ot, const float* __restrict__ ct,
    float* __restrict__ out) {
  constexpr int S_IN = 42, S_OUT = 84, TR = 6, UH = 8, TW = 42, UW = 44;
  __shared__ __align__(16) float sU[24 * UH * UW];   // 8448 floats = 33 KB
  const int blk = blockIdx.x;
  const int b = blk / 28;
  const int rr = blk % 28;
  const int y0 = (rr >> 1) * TR;
  const int x0 = (rr & 1) * TW;
  const int t = threadIdx.x;
  const float* xb = R1 + (size_t)b * 24 * S_IN * S_IN;
  const float sc = (float)(S_IN - 1) / (float)(S_OUT - 1);
  for (int i = t; i < 24 * UH * UW; i += 256) {
    int c = i / (UH * UW), r2 = i % (UH * UW);
    int ry = r2 / UW, cx = r2 % UW;
    int y = y0 + ry - 1, x = x0 + cx - 1;
    float v = 0.f;
    if (y >= 0 && y < S_OUT && x >= 0 && x < S_OUT) {
      float py = y * sc, px = x * sc;
      int ly = (int)py; if (ly > S_IN - 2) ly = S_IN - 2;
      int lx = (int)px; if (lx > S_IN - 2) lx = S_IN - 2;
      float wy = py - (float)ly, wx = px - (float)lx;
      const float* xc = xb + c * S_IN * S_IN + ly * S_IN + lx;
      float v00 = xc[0], v01 = xc[1], v10 = xc[S_IN], v11 = xc[S_IN + 1];
      v = (1.f - wy) * ((1.f - wx) * v00 + wx * v01) +
          wy * ((1.f - wx) * v10 + wx * v11);
    }
    sU[i] = v;
  }
  __syncthreads();
  if (t < 252) {
    const int ry = t / 42, lx = t % 42;
    float acc[24];
#pragma unroll
    for (int o = 0; o < 24; o++) acc[o] = 0.f;
    for (int ic = 0; ic < 24; ic++) {
      const float* urow = &sU[(ic * UH + ry) * UW + lx];
      const float* wp = wt + ic * 216;   // uniform -> s_load
#pragma unroll
      for (int ky = 0; ky < 3; ky++) {
        float x0v = urow[ky * UW + 0];
        float x1v = urow[ky * UW + 1];
        float x2v = urow[ky * UW + 2];
        const float* wk = wp + ky * 72;
#pragma unroll
        for (int o = 0; o < 24; o++)
          acc[o] += wk[o] * x0v + wk[24 + o] * x1v + wk[48 + o] * x2v;
      }
    }
    // residual + relu, kept in registers
    float r[24];
#pragma unroll
    for (int o = 0; o < 24; o++) {
      float u = sU[(o * UH + ry + 1) * UW + lx + 1];
      r[o] = fmaxf(u + acc[o] + bias[o], 0.f);
    }
    // 1x1 conv + sigmoid + flow accumulation (all head params uniform -> SGPR)
    float fy = ct[b * 2 + 0], fx = ct[b * 2 + 1];
    const float* otb_ = ot + b * 2 * KOBJ;
    for (int k = 0; k < KOBJ; k++) {
      float z = c3b[k];
      const float* cw = c3w + k * 24;
#pragma unroll
      for (int c = 0; c < 24; c++) z += r[c] * cw[c];
      float m = 1.f / (1.f + __expf(-z));
      fy += m * otb_[2 * k];
      fx += m * otb_[2 * k + 1];
    }
    const int gy = y0 + ry, gx = x0 + lx;
    const float imgf = 0.01f * 84.0f;
    float ys = imgf * fy + (float)gy;
    float xs = imgf * fx + (float)gx;
    int ix0 = (int)floorf(xs); ix0 = ix0 < 0 ? 0 : (ix0 > 83 ? 83 : ix0);
    int iy0 = (int)floorf(ys); iy0 = iy0 < 0 ? 0 : (iy0 > 83 ? 83 : iy0);
    int ix1 = ix0 + 1 > 83 ? 83 : ix0 + 1;
    int iy1 = iy0 + 1 > 83 ? 83 : iy0 + 1;
    float xc = fminf(fmaxf(xs, 0.f), 83.f);
    float yc = fminf(fmaxf(ys, 0.f), 83.f);
    float wx1 = (float)ix1 - xc, wx0 = xc - (float)ix0;
    float wy1 = (float)iy1 - yc, wy0 = yc - (float)iy0;
    const float* src = inp + ((size_t)b * 2 + 1) * NPIX;
    float Ia = src[iy0 * 84 + ix0], Ib = src[iy1 * 84 + ix0];
    float Ic = src[iy0 * 84 + ix1], Id = src[iy1 * 84 + ix1];
    out[(size_t)b * NPIX + gy * 84 + gx] =
        wx1 * wy1 * Ia + wx1 * wy0 * Ib + wx0 * wy1 * Ic + wx0 * wy0 * Id;
  }
}

}  // namespace

extern "C" void kernel_launch(void* const* d_in, const int* in_sizes, int n_in,
                              void* d_out, int out_size, void* d_ws, size_t ws_size,
                              hipStream_t stream) {
  const float* inp = (const float*)d_in[0];
  const float* cw1 = (const float*)d_in[1];
  const float* cb1 = (const float*)d_in[2];
  const float* cw2 = (const float*)d_in[3];
  const float* cb2 = (const float*)d_in[4];
  const float* cw3 = (const float*)d_in[5];
  const float* cb3 = (const float*)d_in[6];
  const float* fcw = (const float*)d_in[7];
  const float* fcb = (const float*)d_in[8];
  const float* otw = (const float*)d_in[9];
  const float* otb = (const float*)d_in[10];
  const float* ctw = (const float*)d_in[11];
  const float* ctb = (const float*)d_in[12];
  const float* m1w = (const float*)d_in[13];
  const float* m1b = (const float*)d_in[14];
  const float* c1w = (const float*)d_in[15];
  const float* c1b = (const float*)d_in[16];
  const float* c2w = (const float*)d_in[17];
  const float* c2b = (const float*)d_in[18];
  const float* c3w = (const float*)d_in[19];
  const float* c3b = (const float*)d_in[20];
  float* W = (float*)d_ws;
  float* out = (float*)d_out;

  transpose_w<<<(64 * 512 + 255) / 256, 256, 0, stream>>>(cw2, W + OFF_WT2, 64, 512);
  transpose_w<<<(64 * 576 + 255) / 256, 256, 0, stream>>>(cw3, W + OFF_WT3, 64, 576);
  conv1_k<<<512, 256, 0, stream>>>(inp, cw1, cb1, W + OFF_H1);
  conv2_k<<<512, 256, 0, stream>>>(W + OFF_H1, W + OFF_WT2, cb2, W + OFF_H2);
  conv3_k<<<512, 256, 0, stream>>>(W + OFF_H2, W + OFF_WT3, cb3, W + OFF_FEAT);
  // decoder conv weight transposes (WT2/WT3 slots are dead now):
  // [24][24][3][3] -> [ic*9+ky*3+kx][oc]
  transpose_w<<<(24 * 216 + 255) / 256, 256, 0, stream>>>(c1w, W + OFF_WT2, 24, 216);
  transpose_w<<<(24 * 216 + 255) / 256, 256, 0, stream>>>(c2w, W + OFF_WT3, 24, 216);
  // x = relu(feat @ fcw^T + fcb)
  gemm_k<true><<<dim3(8, 8), 256, 0, stream>>>(W + OFF_FEAT, fcw, fcb, W + OFF_X, 512, 3136);
  // heads
  gemm_k<false><<<dim3(1, 8), 256, 0, stream>>>(W + OFF_X, otw, otb, W + OFF_OT, 40, 512);
  gemm_k<false><<<dim3(1, 8), 256, 0, stream>>>(W + OFF_X, ctw, ctb, W + OFF_CT, 2, 512);
  // m0 = x @ m1w^T + m1b   [512, 10584]
  gemm_k<false><<<dim3(166, 8), 256, 0, stream>>>(W + OFF_X, m1w, m1b, W + OFF_M0, 10584, 512);
  // decoder
  upconv1_k<<<512 * 7, 256, 0, stream>>>(W + OFF_M0, W + OFF_WT2, c1b, W + OFF_R1);
  upconv2_final_k<<<512 * 28, 256, 0, stream>>>(W + OFF_R1, inp, W + OFF_WT3, c2b,
                                                c3w, c3b, W + OFF_OT, W + OFF_CT, out);
}

// Round 2
// 1340.411 us; speedup vs baseline: 1.3778x; 1.1151x over previous
//
#include <hip/hip_runtime.h>
#include <math.h>

namespace {

typedef float f32x2 __attribute__((ext_vector_type(2)));

#if defined(__has_builtin)
#if __has_builtin(__builtin_elementwise_fma)
#define HAVE_EW_FMA 1
#endif
#endif

__device__ __forceinline__ f32x2 pkfma(f32x2 a, f32x2 b, f32x2 c) {
#ifdef HAVE_EW_FMA
  return __builtin_elementwise_fma(a, b, c);
#else
  return a * b + c;   // -ffp-contract=fast fuses per element
#endif
}

constexpr int IMS  = 84;
constexpr int NPIX = IMS * IMS;      // 7056
constexpr int KOBJ = 20;

// ---- workspace layout (float offsets), peak = 27448320 floats = 110 MB ----
constexpr size_t OFF_X    = 0;            // 512*512            -> 262144
constexpr size_t OFF_OT   = 262144;       // 512*40             -> 282624
constexpr size_t OFF_CT   = 282624;       // 512*2 (pad)        -> 283648
constexpr size_t OFF_WT2  = 283648;       // 512*64             -> 316416
constexpr size_t OFF_WT3  = 316416;       // 576*64             -> 353280
constexpr size_t OFF_M0   = 353280;       // 512*10584          -> 5772288
constexpr size_t OFF_R1   = 5772288;      // 512*24*42*42       -> 27448320
// H1/H2/FEAT alias into the R1 region (dead before upconv1 writes R1)
constexpr size_t OFF_H1   = OFF_R1;       // 512*32*400         -> 12325888
constexpr size_t OFF_H2   = 12325888;     // 512*64*81          -> 14980096
constexpr size_t OFF_FEAT = 14980096;     // 512*3136           -> 16585728
// decoder conv weights (transposed, 5184 floats each) reuse WT2/WT3 slots
// after conv2/conv3 are done with them.

// ---- generic weight transpose: w[oc][ckk] -> wt[ckk][oc] ----
__global__ void transpose_w(const float* __restrict__ w, float* __restrict__ wt,
                            int OC, int CKK) {
  int idx = blockIdx.x * 256 + threadIdx.x;
  if (idx < OC * CKK) {
    int oc = idx / CKK, ckk = idx % CKK;
    wt[ckk * OC + oc] = w[idx];
  }
}

// ---- conv1: [B,2,84,84] -> [B,32,20,20], k=8 s=4, relu. LDS 44.6 KB ----
__global__ __launch_bounds__(256) void conv1_k(
    const float* __restrict__ inp, const float* __restrict__ w,
    const float* __restrict__ bias, float* __restrict__ out) {
  __shared__ __align__(16) float sIn[NPIX];      // one channel at a time
  __shared__ __align__(16) float sW[128 * 32];   // [c][u][v][oc]
  const int b = blockIdx.x, t = threadIdx.x;
  for (int i = t; i < 4096; i += 256) {
    int oc = i >> 7, ckk = i & 127;
    sW[ckk * 32 + oc] = w[i];
  }
  const float* ip = inp + (size_t)b * 2 * NPIX;
  const int oc0 = (t & 7) * 4;
  const int pg  = t >> 3;
  int ibase[13];
#pragma unroll
  for (int k = 0; k < 13; k++) {
    int p = pg + 32 * k; if (p > 399) p = 399;
    ibase[k] = (p / 20) * 4 * 84 + (p % 20) * 4;
  }
  f32x2 acc[13][2];
#pragma unroll
  for (int k = 0; k < 13; k++) { acc[k][0] = f32x2{0.f, 0.f}; acc[k][1] = f32x2{0.f, 0.f}; }
  for (int c = 0; c < 2; c++) {
    __syncthreads();
    for (int i = t; i < NPIX; i += 256) sIn[i] = ip[c * NPIX + i];
    __syncthreads();
    for (int u = 0; u < 8; u++) {
#pragma unroll
      for (int v = 0; v < 8; v++) {
        const float4 wv = *(const float4*)&sW[((c * 8 + u) * 8 + v) * 32 + oc0];
        const f32x2 w0 = {wv.x, wv.y}, w1 = {wv.z, wv.w};
        const int off = u * 84 + v;
#pragma unroll
        for (int k = 0; k < 13; k++) {
          float x = sIn[off + ibase[k]];
          f32x2 xv = {x, x};
          acc[k][0] = pkfma(w0, xv, acc[k][0]);
          acc[k][1] = pkfma(w1, xv, acc[k][1]);
        }
      }
    }
  }
  float b0 = bias[oc0], b1 = bias[oc0+1], b2 = bias[oc0+2], b3 = bias[oc0+3];
  float* op = out + (size_t)b * 32 * 400;
#pragma unroll
  for (int k = 0; k < 13; k++) {
    int p = pg + 32 * k;
    if (p < 400) {
      op[(oc0+0)*400 + p] = fmaxf(acc[k][0][0] + b0, 0.f);
      op[(oc0+1)*400 + p] = fmaxf(acc[k][0][1] + b1, 0.f);
      op[(oc0+2)*400 + p] = fmaxf(acc[k][1][0] + b2, 0.f);
      op[(oc0+3)*400 + p] = fmaxf(acc[k][1][1] + b3, 0.f);
    }
  }
}

// ---- conv2: [B,32,20,20] -> [B,64,9,9], k=4 s=2, relu. LDS 51.2 KB ----
__global__ __launch_bounds__(256) void conv2_k(
    const float* __restrict__ in, const float* __restrict__ wt,
    const float* __restrict__ bias, float* __restrict__ out) {
  __shared__ float sIn[32 * 400];
  const int b = blockIdx.x, t = threadIdx.x;
  const float* ip = in + (size_t)b * 12800;
  for (int i = t; i < 12800; i += 256) sIn[i] = ip[i];
  __syncthreads();
  const int oc0 = (t & 7) * 8;
  const int pg  = t >> 3;
  int base[3];
#pragma unroll
  for (int k = 0; k < 3; k++) {
    int p = pg + 32 * k; if (p > 80) p = 80;
    base[k] = (p / 9) * 40 + (p % 9) * 2;
  }
  f32x2 acc[3][4];
#pragma unroll
  for (int k = 0; k < 3; k++)
#pragma unroll
    for (int o = 0; o < 4; o++) acc[k][o] = f32x2{0.f, 0.f};
  for (int c = 0; c < 32; c++) {
#pragma unroll
    for (int u = 0; u < 4; u++)
#pragma unroll
      for (int v = 0; v < 4; v++) {
        const float* wp = wt + ((c * 4 + u) * 4 + v) * 64 + oc0;
        float4 wa = *(const float4*)wp;
        float4 wb = *(const float4*)(wp + 4);
        const f32x2 w0 = {wa.x, wa.y}, w1 = {wa.z, wa.w};
        const f32x2 w2 = {wb.x, wb.y}, w3 = {wb.z, wb.w};
        int off = c * 400 + u * 20 + v;
#pragma unroll
        for (int k = 0; k < 3; k++) {
          float x = sIn[off + base[k]];
          f32x2 xv = {x, x};
          acc[k][0] = pkfma(w0, xv, acc[k][0]);
          acc[k][1] = pkfma(w1, xv, acc[k][1]);
          acc[k][2] = pkfma(w2, xv, acc[k][2]);
          acc[k][3] = pkfma(w3, xv, acc[k][3]);
        }
      }
  }
  float* op = out + (size_t)b * 5184;
#pragma unroll
  for (int k = 0; k < 3; k++) {
    int p = pg + 32 * k;
    if (p < 81) {
#pragma unroll
      for (int o = 0; o < 8; o++)
        op[(oc0+o)*81 + p] = fmaxf(acc[k][o >> 1][o & 1] + bias[oc0+o], 0.f);
    }
  }
}

// ---- conv3: [B,64,9,9] -> feat [B,3136] (= [64][7][7] flat), k=3 s=1, relu ----
__global__ __launch_bounds__(256) void conv3_k(
    const float* __restrict__ in, const float* __restrict__ wt,
    const float* __restrict__ bias, float* __restrict__ out) {
  __shared__ float sIn[64 * 81];
  const int b = blockIdx.x, t = threadIdx.x;
  const float* ip = in + (size_t)b * 5184;
  for (int i = t; i < 5184; i += 256) sIn[i] = ip[i];
  __syncthreads();
  const int oc0 = (t & 7) * 8;
  const int pg  = t >> 3;
  int base[2];
#pragma unroll
  for (int k = 0; k < 2; k++) {
    int p = pg + 32 * k; if (p > 48) p = 48;
    base[k] = (p / 7) * 9 + (p % 7);
  }
  f32x2 acc[2][4];
#pragma unroll
  for (int k = 0; k < 2; k++)
#pragma unroll
    for (int o = 0; o < 4; o++) acc[k][o] = f32x2{0.f, 0.f};
  for (int c = 0; c < 64; c++) {
#pragma unroll
    for (int u = 0; u < 3; u++)
#pragma unroll
      for (int v = 0; v < 3; v++) {
        const float* wp = wt + ((c * 3 + u) * 3 + v) * 64 + oc0;
        float4 wa = *(const float4*)wp;
        float4 wb = *(const float4*)(wp + 4);
        const f32x2 w0 = {wa.x, wa.y}, w1 = {wa.z, wa.w};
        const f32x2 w2 = {wb.x, wb.y}, w3 = {wb.z, wb.w};
        int off = c * 81 + u * 9 + v;
#pragma unroll
        for (int k = 0; k < 2; k++) {
          float x = sIn[off + base[k]];
          f32x2 xv = {x, x};
          acc[k][0] = pkfma(w0, xv, acc[k][0]);
          acc[k][1] = pkfma(w1, xv, acc[k][1]);
          acc[k][2] = pkfma(w2, xv, acc[k][2]);
          acc[k][3] = pkfma(w3, xv, acc[k][3]);
        }
      }
  }
  float* op = out + (size_t)b * 3136;
#pragma unroll
  for (int k = 0; k < 2; k++) {
    int p = pg + 32 * k;
    if (p < 49) {
#pragma unroll
      for (int o = 0; o < 8; o++)
        op[(oc0+o)*49 + p] = fmaxf(acc[k][o >> 1][o & 1] + bias[oc0+o], 0.f);
    }
  }
}

// ---- GEMM: C[M,N] = A[M,K] @ W[N,K]^T + bias, optional relu. M=512, K%16==0 ----
template<bool RELU>
__global__ __launch_bounds__(256) void gemm_k(
    const float* __restrict__ A, const float* __restrict__ Wm,
    const float* __restrict__ bias, float* __restrict__ C,
    int N, int K) {
  __shared__ __align__(16) float As[16][68];
  __shared__ __align__(16) float Ws[16][68];
  const int t = threadIdx.x;
  const int m0 = blockIdx.y * 64, n0 = blockIdx.x * 64;
  const int r  = t >> 2;
  const int kq = (t & 3) * 4;
  const int r0 = (t >> 4) * 4, c0 = (t & 15) * 4;
  f32x2 acc[4][2];
#pragma unroll
  for (int i = 0; i < 4; i++) { acc[i][0] = f32x2{0.f, 0.f}; acc[i][1] = f32x2{0.f, 0.f}; }
  for (int k0 = 0; k0 < K; k0 += 16) {
    float4 a = *(const float4*)(A + (size_t)(m0 + r) * K + k0 + kq);
    int wrow = n0 + r;
    float4 wv = make_float4(0.f, 0.f, 0.f, 0.f);
    if (wrow < N) wv = *(const float4*)(Wm + (size_t)wrow * K + k0 + kq);
    __syncthreads();
    As[kq+0][r] = a.x; As[kq+1][r] = a.y; As[kq+2][r] = a.z; As[kq+3][r] = a.w;
    Ws[kq+0][r] = wv.x; Ws[kq+1][r] = wv.y; Ws[kq+2][r] = wv.z; Ws[kq+3][r] = wv.w;
    __syncthreads();
#pragma unroll
    for (int kk = 0; kk < 16; kk++) {
      float4 av = *(const float4*)&As[kk][r0];
      float4 bv = *(const float4*)&Ws[kk][c0];
      const f32x2 b0 = {bv.x, bv.y}, b1 = {bv.z, bv.w};
      float ar[4] = {av.x, av.y, av.z, av.w};
#pragma unroll
      for (int i = 0; i < 4; i++) {
        f32x2 ai = {ar[i], ar[i]};
        acc[i][0] = pkfma(b0, ai, acc[i][0]);
        acc[i][1] = pkfma(b1, ai, acc[i][1]);
      }
    }
  }
#pragma unroll
  for (int i = 0; i < 4; i++) {
    int row = m0 + r0 + i;
#pragma unroll
    for (int j = 0; j < 4; j++) {
      int col = n0 + c0 + j;
      if (col < N) {
        float v = acc[i][j >> 1][j & 1] + bias[col];
        C[(size_t)row * N + col] = RELU ? fmaxf(v, 0.f) : v;
      }
    }
  }
}

// ---- upconv1: upsample 21->42 + residual 3x3 conv + relu.
//      One thread per output pixel, all 24 oc as 12 packed-f32 pairs;
//      weights pre-transposed [ic][ky][kx][oc] and wave-uniform -> SGPR pairs.
__global__ __launch_bounds__(256, 4) void upconv1_k(
    const float* __restrict__ X, const float* __restrict__ wt,
    const float* __restrict__ bias, float* __restrict__ out) {
  constexpr int S_IN = 21, S_OUT = 42, TR = 6, UH = 8, UW = 44, NTILE = 7;
  __shared__ __align__(16) float sU[24 * UH * UW];   // 8448 floats = 33 KB
  const int b = blockIdx.x / NTILE;
  const int y0 = (blockIdx.x % NTILE) * TR;
  const int t = threadIdx.x;
  const float* xb = X + (size_t)b * 24 * S_IN * S_IN;
  const float sc = (float)(S_IN - 1) / (float)(S_OUT - 1);
  for (int i = t; i < 24 * UH * UW; i += 256) {
    int c = i / (UH * UW), rr = i % (UH * UW);
    int ry = rr / UW, cx = rr % UW;
    int y = y0 + ry - 1, x = cx - 1;
    float v = 0.f;
    if (y >= 0 && y < S_OUT && x >= 0 && x < S_OUT) {
      float py = y * sc, px = x * sc;
      int ly = (int)py; if (ly > S_IN - 2) ly = S_IN - 2;
      int lx = (int)px; if (lx > S_IN - 2) lx = S_IN - 2;
      float wy = py - (float)ly, wx = px - (float)lx;
      const float* xc = xb + c * S_IN * S_IN + ly * S_IN + lx;
      f32x2 a = {xc[0], xc[S_IN]};          // {v00, v10}
      f32x2 bb = {xc[1], xc[S_IN + 1]};     // {v01, v11}
      f32x2 wxv = {wx, wx};
      f32x2 h = pkfma(wxv, bb - a, a);      // {h_top, h_bot}
      v = h[0] + wy * (h[1] - h[0]);
    }
    sU[i] = v;
  }
  __syncthreads();
  if (t < 252) {
    const int ry = t / 42, lx = t % 42;
    f32x2 acc[12];
#pragma unroll
    for (int j = 0; j < 12; j++) acc[j] = f32x2{0.f, 0.f};
    for (int ic = 0; ic < 24; ic++) {
      const float* urow = &sU[(ic * UH + ry) * UW + lx];
      const float* wp = wt + ic * 216;   // [3][3][24], uniform -> s_load
#pragma unroll
      for (int ky = 0; ky < 3; ky++) {
        float x0v = urow[ky * UW + 0];
        float x1v = urow[ky * UW + 1];
        float x2v = urow[ky * UW + 2];
        f32x2 X0 = {x0v, x0v}, X1 = {x1v, x1v}, X2 = {x2v, x2v};
        const f32x2* wk2 = (const f32x2*)(wp + ky * 72);
#pragma unroll
        for (int j = 0; j < 12; j++)
          acc[j] = pkfma(wk2[j], X0,
                   pkfma(wk2[12 + j], X1,
                   pkfma(wk2[24 + j], X2, acc[j])));
      }
    }
    const int yy = y0 + ry;
#pragma unroll
    for (int j = 0; j < 12; j++) {
      f32x2 u2 = { sU[((2*j)   * UH + ry + 1) * UW + lx + 1],
                   sU[((2*j+1) * UH + ry + 1) * UW + lx + 1] };
      f32x2 b2 = *(const f32x2*)&bias[2*j];
      f32x2 s = u2 + acc[j] + b2;
      out[(((size_t)b * 24 + 2*j    ) * S_OUT + yy) * S_OUT + lx] = fmaxf(s[0], 0.f);
      out[(((size_t)b * 24 + 2*j + 1) * S_OUT + yy) * S_OUT + lx] = fmaxf(s[1], 0.f);
    }
  }
}

// ---- fused: upsample 42->84 + residual conv + relu + 1x1 conv + sigmoid
//      + flow + bilinear warp.  One thread per pixel; 24 channels as 12
//      packed-f32 pairs; head params uniform -> SGPR.  LDS 33 KB. ----
__global__ __launch_bounds__(256, 4) void upconv2_final_k(
    const float* __restrict__ R1, const float* __restrict__ inp,
    const float* __restrict__ wt, const float* __restrict__ bias,
    const float* __restrict__ c3w, const float* __restrict__ c3b,
    const float* __restrict__ ot, const float* __restrict__ ct,
    float* __restrict__ out) {
  constexpr int S_IN = 42, S_OUT = 84, TR = 6, UH = 8, TW = 42, UW = 44;
  __shared__ __align__(16) float sU[24 * UH * UW];   // 8448 floats = 33 KB
  const int blk = blockIdx.x;
  const int b = blk / 28;
  const int rr = blk % 28;
  const int y0 = (rr >> 1) * TR;
  const int x0 = (rr & 1) * TW;
  const int t = threadIdx.x;
  const float* xb = R1 + (size_t)b * 24 * S_IN * S_IN;
  const float sc = (float)(S_IN - 1) / (float)(S_OUT - 1);
  for (int i = t; i < 24 * UH * UW; i += 256) {
    int c = i / (UH * UW), r2 = i % (UH * UW);
    int ry = r2 / UW, cx = r2 % UW;
    int y = y0 + ry - 1, x = x0 + cx - 1;
    float v = 0.f;
    if (y >= 0 && y < S_OUT && x >= 0 && x < S_OUT) {
      float py = y * sc, px = x * sc;
      int ly = (int)py; if (ly > S_IN - 2) ly = S_IN - 2;
      int lx = (int)px; if (lx > S_IN - 2) lx = S_IN - 2;
      float wy = py - (float)ly, wx = px - (float)lx;
      const float* xc = xb + c * S_IN * S_IN + ly * S_IN + lx;
      f32x2 a = {xc[0], xc[S_IN]};
      f32x2 bb = {xc[1], xc[S_IN + 1]};
      f32x2 wxv = {wx, wx};
      f32x2 h = pkfma(wxv, bb - a, a);
      v = h[0] + wy * (h[1] - h[0]);
    }
    sU[i] = v;
  }
  __syncthreads();
  if (t < 252) {
    const int ry = t / 42, lx = t % 42;
    f32x2 acc[12];
#pragma unroll
    for (int j = 0; j < 12; j++) acc[j] = f32x2{0.f, 0.f};
    for (int ic = 0; ic < 24; ic++) {
      const float* urow = &sU[(ic * UH + ry) * UW + lx];
      const float* wp = wt + ic * 216;   // uniform -> s_load
#pragma unroll
      for (int ky = 0; ky < 3; ky++) {
        float x0v = urow[ky * UW + 0];
        float x1v = urow[ky * UW + 1];
        float x2v = urow[ky * UW + 2];
        f32x2 X0 = {x0v, x0v}, X1 = {x1v, x1v}, X2 = {x2v, x2v};
        const f32x2* wk2 = (const f32x2*)(wp + ky * 72);
#pragma unroll
        for (int j = 0; j < 12; j++)
          acc[j] = pkfma(wk2[j], X0,
                   pkfma(wk2[12 + j], X1,
                   pkfma(wk2[24 + j], X2, acc[j])));
      }
    }
    // residual + relu, kept in register pairs
    f32x2 r[12];
#pragma unroll
    for (int j = 0; j < 12; j++) {
      f32x2 u2 = { sU[((2*j)   * UH + ry + 1) * UW + lx + 1],
                   sU[((2*j+1) * UH + ry + 1) * UW + lx + 1] };
      f32x2 b2 = *(const f32x2*)&bias[2*j];
      f32x2 s = u2 + acc[j] + b2;
      r[j][0] = fmaxf(s[0], 0.f);
      r[j][1] = fmaxf(s[1], 0.f);
    }
    // 1x1 conv + sigmoid + flow accumulation (head params uniform -> SGPR)
    f32x2 f2 = *(const f32x2*)&ct[b * 2];            // {fy, fx}
    const f32x2* ot2 = (const f32x2*)(ot + b * 2 * KOBJ);
    for (int k = 0; k < KOBJ; k++) {
      f32x2 zv = {c3b[k], 0.f};
      const f32x2* cw2 = (const f32x2*)(c3w + k * 24);
#pragma unroll
      for (int j = 0; j < 12; j++) zv = pkfma(r[j], cw2[j], zv);
      float z = zv[0] + zv[1];
      float m = 1.f / (1.f + __expf(-z));
      f32x2 mv = {m, m};
      f2 = pkfma(mv, ot2[k], f2);
    }
    const int gy = y0 + ry, gx = x0 + lx;
    const float imgf = 0.01f * 84.0f;
    float ys = imgf * f2[0] + (float)gy;
    float xs = imgf * f2[1] + (float)gx;
    int ix0 = (int)floorf(xs); ix0 = ix0 < 0 ? 0 : (ix0 > 83 ? 83 : ix0);
    int iy0 = (int)floorf(ys); iy0 = iy0 < 0 ? 0 : (iy0 > 83 ? 83 : iy0);
    int ix1 = ix0 + 1 > 83 ? 83 : ix0 + 1;
    int iy1 = iy0 + 1 > 83 ? 83 : iy0 + 1;
    float xc = fminf(fmaxf(xs, 0.f), 83.f);
    float yc = fminf(fmaxf(ys, 0.f), 83.f);
    float wx1 = (float)ix1 - xc, wx0 = xc - (float)ix0;
    float wy1 = (float)iy1 - yc, wy0 = yc - (float)iy0;
    const float* src = inp + ((size_t)b * 2 + 1) * NPIX;
    float Ia = src[iy0 * 84 + ix0], Ib = src[iy1 * 84 + ix0];
    float Ic = src[iy0 * 84 + ix1], Id = src[iy1 * 84 + ix1];
    out[(size_t)b * NPIX + gy * 84 + gx] =
        wx1 * wy1 * Ia + wx1 * wy0 * Ib + wx0 * wy1 * Ic + wx0 * wy0 * Id;
  }
}

}  // namespace

extern "C" void kernel_launch(void* const* d_in, const int* in_sizes, int n_in,
                              void* d_out, int out_size, void* d_ws, size_t ws_size,
                              hipStream_t stream) {
  const float* inp = (const float*)d_in[0];
  const float* cw1 = (const float*)d_in[1];
  const float* cb1 = (const float*)d_in[2];
  const float* cw2 = (const float*)d_in[3];
  const float* cb2 = (const float*)d_in[4];
  const float* cw3 = (const float*)d_in[5];
  const float* cb3 = (const float*)d_in[6];
  const float* fcw = (const float*)d_in[7];
  const float* fcb = (const float*)d_in[8];
  const float* otw = (const float*)d_in[9];
  const float* otb = (const float*)d_in[10];
  const float* ctw = (const float*)d_in[11];
  const float* ctb = (const float*)d_in[12];
  const float* m1w = (const float*)d_in[13];
  const float* m1b = (const float*)d_in[14];
  const float* c1w = (const float*)d_in[15];
  const float* c1b = (const float*)d_in[16];
  const float* c2w = (const float*)d_in[17];
  const float* c2b = (const float*)d_in[18];
  const float* c3w = (const float*)d_in[19];
  const float* c3b = (const float*)d_in[20];
  float* W = (float*)d_ws;
  float* out = (float*)d_out;

  transpose_w<<<(64 * 512 + 255) / 256, 256, 0, stream>>>(cw2, W + OFF_WT2, 64, 512);
  transpose_w<<<(64 * 576 + 255) / 256, 256, 0, stream>>>(cw3, W + OFF_WT3, 64, 576);
  conv1_k<<<512, 256, 0, stream>>>(inp, cw1, cb1, W + OFF_H1);
  conv2_k<<<512, 256, 0, stream>>>(W + OFF_H1, W + OFF_WT2, cb2, W + OFF_H2);
  conv3_k<<<512, 256, 0, stream>>>(W + OFF_H2, W + OFF_WT3, cb3, W + OFF_FEAT);
  // decoder conv weight transposes (WT2/WT3 slots are dead now):
  // [24][24][3][3] -> [ic*9+ky*3+kx][oc]
  transpose_w<<<(24 * 216 + 255) / 256, 256, 0, stream>>>(c1w, W + OFF_WT2, 24, 216);
  transpose_w<<<(24 * 216 + 255) / 256, 256, 0, stream>>>(c2w, W + OFF_WT3, 24, 216);
  // x = relu(feat @ fcw^T + fcb)
  gemm_k<true><<<dim3(8, 8), 256, 0, stream>>>(W + OFF_FEAT, fcw, fcb, W + OFF_X, 512, 3136);
  // heads
  gemm_k<false><<<dim3(1, 8), 256, 0, stream>>>(W + OFF_X, otw, otb, W + OFF_OT, 40, 512);
  gemm_k<false><<<dim3(1, 8), 256, 0, stream>>>(W + OFF_X, ctw, ctb, W + OFF_CT, 2, 512);
  // m0 = x @ m1w^T + m1b   [512, 10584]
  gemm_k<false><<<dim3(166, 8), 256, 0, stream>>>(W + OFF_X, m1w, m1b, W + OFF_M0, 10584, 512);
  // decoder
  upconv1_k<<<512 * 7, 256, 0, stream>>>(W + OFF_M0, W + OFF_WT2, c1b, W + OFF_R1);
  upconv2_final_k<<<512 * 28, 256, 0, stream>>>(W + OFF_R1, inp, W + OFF_WT3, c2b,
                                                c3w, c3b, W + OFF_OT, W + OFF_CT, out);
}

// Round 3
// 1203.849 us; speedup vs baseline: 1.5341x; 1.1134x over previous
//
#include <hip/hip_runtime.h>
#include <math.h>

namespace {

typedef float f32x2 __attribute__((ext_vector_type(2)));

#if defined(__has_builtin)
#if __has_builtin(__builtin_elementwise_fma)
#define HAVE_EW_FMA 1
#endif
#endif

__device__ __forceinline__ f32x2 pkfma(f32x2 a, f32x2 b, f32x2 c) {
#ifdef HAVE_EW_FMA
  return __builtin_elementwise_fma(a, b, c);
#else
  return a * b + c;   // -ffp-contract=fast fuses per element
#endif
}

constexpr int IMS  = 84;
constexpr int NPIX = IMS * IMS;      // 7056
constexpr int KOBJ = 20;

// ---- workspace layout (float offsets), peak = 27448320 floats = 110 MB ----
constexpr size_t OFF_X    = 0;            // 512*512            -> 262144
constexpr size_t OFF_OT   = 262144;       // 512*40             -> 282624
constexpr size_t OFF_CT   = 282624;       // 512*2 (pad)        -> 283648
constexpr size_t OFF_WT2  = 283648;       // 512*64             -> 316416
constexpr size_t OFF_WT3  = 316416;       // 576*64             -> 353280
constexpr size_t OFF_M0   = 353280;       // 512*10584          -> 5772288
constexpr size_t OFF_R1   = 5772288;      // 512*24*42*42       -> 27448320
// H1/H2/FEAT alias into the R1 region (dead before upconv1 writes R1)
constexpr size_t OFF_H1   = OFF_R1;       // 512*32*400         -> 12325888
constexpr size_t OFF_H2   = 12325888;     // 512*64*81          -> 14980096
constexpr size_t OFF_FEAT = 14980096;     // 512*3136           -> 16585728
// decoder conv weights (transposed, 5184 floats each) reuse WT2/WT3 slots
// after conv2/conv3 are done with them.

// ---- generic weight transpose: w[oc][ckk] -> wt[ckk][oc] ----
__global__ void transpose_w(const float* __restrict__ w, float* __restrict__ wt,
                            int OC, int CKK) {
  int idx = blockIdx.x * 256 + threadIdx.x;
  if (idx < OC * CKK) {
    int oc = idx / CKK, ckk = idx % CKK;
    wt[ckk * OC + oc] = w[idx];
  }
}

// ---- conv1: [B,2,84,84] -> [B,32,20,20], k=8 s=4, relu. LDS 44.6 KB ----
__global__ __launch_bounds__(256) void conv1_k(
    const float* __restrict__ inp, const float* __restrict__ w,
    const float* __restrict__ bias, float* __restrict__ out) {
  __shared__ __align__(16) float sIn[NPIX];      // one channel at a time
  __shared__ __align__(16) float sW[128 * 32];   // [c][u][v][oc]
  const int b = blockIdx.x, t = threadIdx.x;
  for (int i = t; i < 4096; i += 256) {
    int oc = i >> 7, ckk = i & 127;
    sW[ckk * 32 + oc] = w[i];
  }
  const float* ip = inp + (size_t)b * 2 * NPIX;
  const int oc0 = (t & 7) * 4;
  const int pg  = t >> 3;
  int ibase[13];
#pragma unroll
  for (int k = 0; k < 13; k++) {
    int p = pg + 32 * k; if (p > 399) p = 399;
    ibase[k] = (p / 20) * 4 * 84 + (p % 20) * 4;
  }
  f32x2 acc[13][2];
#pragma unroll
  for (int k = 0; k < 13; k++) { acc[k][0] = f32x2{0.f, 0.f}; acc[k][1] = f32x2{0.f, 0.f}; }
  for (int c = 0; c < 2; c++) {
    __syncthreads();
    for (int i = t; i < NPIX; i += 256) sIn[i] = ip[c * NPIX + i];
    __syncthreads();
    for (int u = 0; u < 8; u++) {
#pragma unroll
      for (int v = 0; v < 8; v++) {
        const float4 wv = *(const float4*)&sW[((c * 8 + u) * 8 + v) * 32 + oc0];
        const f32x2 w0 = {wv.x, wv.y}, w1 = {wv.z, wv.w};
        const int off = u * 84 + v;
#pragma unroll
        for (int k = 0; k < 13; k++) {
          float x = sIn[off + ibase[k]];
          f32x2 xv = {x, x};
          acc[k][0] = pkfma(w0, xv, acc[k][0]);
          acc[k][1] = pkfma(w1, xv, acc[k][1]);
        }
      }
    }
  }
  float b0 = bias[oc0], b1 = bias[oc0+1], b2 = bias[oc0+2], b3 = bias[oc0+3];
  float* op = out + (size_t)b * 32 * 400;
#pragma unroll
  for (int k = 0; k < 13; k++) {
    int p = pg + 32 * k;
    if (p < 400) {
      op[(oc0+0)*400 + p] = fmaxf(acc[k][0][0] + b0, 0.f);
      op[(oc0+1)*400 + p] = fmaxf(acc[k][0][1] + b1, 0.f);
      op[(oc0+2)*400 + p] = fmaxf(acc[k][1][0] + b2, 0.f);
      op[(oc0+3)*400 + p] = fmaxf(acc[k][1][1] + b3, 0.f);
    }
  }
}

// ---- conv2: [B,32,20,20] -> [B,64,9,9], k=4 s=2, relu. LDS 51.2 KB ----
__global__ __launch_bounds__(256) void conv2_k(
    const float* __restrict__ in, const float* __restrict__ wt,
    const float* __restrict__ bias, float* __restrict__ out) {
  __shared__ float sIn[32 * 400];
  const int b = blockIdx.x, t = threadIdx.x;
  const float* ip = in + (size_t)b * 12800;
  for (int i = t; i < 12800; i += 256) sIn[i] = ip[i];
  __syncthreads();
  const int oc0 = (t & 7) * 8;
  const int pg  = t >> 3;
  int base[3];
#pragma unroll
  for (int k = 0; k < 3; k++) {
    int p = pg + 32 * k; if (p > 80) p = 80;
    base[k] = (p / 9) * 40 + (p % 9) * 2;
  }
  f32x2 acc[3][4];
#pragma unroll
  for (int k = 0; k < 3; k++)
#pragma unroll
    for (int o = 0; o < 4; o++) acc[k][o] = f32x2{0.f, 0.f};
  for (int c = 0; c < 32; c++) {
#pragma unroll
    for (int u = 0; u < 4; u++)
#pragma unroll
      for (int v = 0; v < 4; v++) {
        const float* wp = wt + ((c * 4 + u) * 4 + v) * 64 + oc0;
        float4 wa = *(const float4*)wp;
        float4 wb = *(const float4*)(wp + 4);
        const f32x2 w0 = {wa.x, wa.y}, w1 = {wa.z, wa.w};
        const f32x2 w2 = {wb.x, wb.y}, w3 = {wb.z, wb.w};
        int off = c * 400 + u * 20 + v;
#pragma unroll
        for (int k = 0; k < 3; k++) {
          float x = sIn[off + base[k]];
          f32x2 xv = {x, x};
          acc[k][0] = pkfma(w0, xv, acc[k][0]);
          acc[k][1] = pkfma(w1, xv, acc[k][1]);
          acc[k][2] = pkfma(w2, xv, acc[k][2]);
          acc[k][3] = pkfma(w3, xv, acc[k][3]);
        }
      }
  }
  float* op = out + (size_t)b * 5184;
#pragma unroll
  for (int k = 0; k < 3; k++) {
    int p = pg + 32 * k;
    if (p < 81) {
#pragma unroll
      for (int o = 0; o < 8; o++)
        op[(oc0+o)*81 + p] = fmaxf(acc[k][o >> 1][o & 1] + bias[oc0+o], 0.f);
    }
  }
}

// ---- conv3: [B,64,9,9] -> feat [B,3136] (= [64][7][7] flat), k=3 s=1, relu ----
__global__ __launch_bounds__(256) void conv3_k(
    const float* __restrict__ in, const float* __restrict__ wt,
    const float* __restrict__ bias, float* __restrict__ out) {
  __shared__ float sIn[64 * 81];
  const int b = blockIdx.x, t = threadIdx.x;
  const float* ip = in + (size_t)b * 5184;
  for (int i = t; i < 5184; i += 256) sIn[i] = ip[i];
  __syncthreads();
  const int oc0 = (t & 7) * 8;
  const int pg  = t >> 3;
  int base[2];
#pragma unroll
  for (int k = 0; k < 2; k++) {
    int p = pg + 32 * k; if (p > 48) p = 48;
    base[k] = (p / 7) * 9 + (p % 7);
  }
  f32x2 acc[2][4];
#pragma unroll
  for (int k = 0; k < 2; k++)
#pragma unroll
    for (int o = 0; o < 4; o++) acc[k][o] = f32x2{0.f, 0.f};
  for (int c = 0; c < 64; c++) {
#pragma unroll
    for (int u = 0; u < 3; u++)
#pragma unroll
      for (int v = 0; v < 3; v++) {
        const float* wp = wt + ((c * 3 + u) * 3 + v) * 64 + oc0;
        float4 wa = *(const float4*)wp;
        float4 wb = *(const float4*)(wp + 4);
        const f32x2 w0 = {wa.x, wa.y}, w1 = {wa.z, wa.w};
        const f32x2 w2 = {wb.x, wb.y}, w3 = {wb.z, wb.w};
        int off = c * 81 + u * 9 + v;
#pragma unroll
        for (int k = 0; k < 2; k++) {
          float x = sIn[off + base[k]];
          f32x2 xv = {x, x};
          acc[k][0] = pkfma(w0, xv, acc[k][0]);
          acc[k][1] = pkfma(w1, xv, acc[k][1]);
          acc[k][2] = pkfma(w2, xv, acc[k][2]);
          acc[k][3] = pkfma(w3, xv, acc[k][3]);
        }
      }
  }
  float* op = out + (size_t)b * 3136;
#pragma unroll
  for (int k = 0; k < 2; k++) {
    int p = pg + 32 * k;
    if (p < 49) {
#pragma unroll
      for (int o = 0; o < 8; o++)
        op[(oc0+o)*49 + p] = fmaxf(acc[k][o >> 1][o & 1] + bias[oc0+o], 0.f);
    }
  }
}

// ---- GEMM: C[M,N] = A[M,K] @ W[N,K]^T + bias, optional relu. M=512, K%16==0 ----
template<bool RELU>
__global__ __launch_bounds__(256) void gemm_k(
    const float* __restrict__ A, const float* __restrict__ Wm,
    const float* __restrict__ bias, float* __restrict__ C,
    int N, int K) {
  __shared__ __align__(16) float As[16][68];
  __shared__ __align__(16) float Ws[16][68];
  const int t = threadIdx.x;
  const int m0 = blockIdx.y * 64, n0 = blockIdx.x * 64;
  const int r  = t >> 2;
  const int kq = (t & 3) * 4;
  const int r0 = (t >> 4) * 4, c0 = (t & 15) * 4;
  f32x2 acc[4][2];
#pragma unroll
  for (int i = 0; i < 4; i++) { acc[i][0] = f32x2{0.f, 0.f}; acc[i][1] = f32x2{0.f, 0.f}; }
  for (int k0 = 0; k0 < K; k0 += 16) {
    float4 a = *(const float4*)(A + (size_t)(m0 + r) * K + k0 + kq);
    int wrow = n0 + r;
    float4 wv = make_float4(0.f, 0.f, 0.f, 0.f);
    if (wrow < N) wv = *(const float4*)(Wm + (size_t)wrow * K + k0 + kq);
    __syncthreads();
    As[kq+0][r] = a.x; As[kq+1][r] = a.y; As[kq+2][r] = a.z; As[kq+3][r] = a.w;
    Ws[kq+0][r] = wv.x; Ws[kq+1][r] = wv.y; Ws[kq+2][r] = wv.z; Ws[kq+3][r] = wv.w;
    __syncthreads();
#pragma unroll
    for (int kk = 0; kk < 16; kk++) {
      float4 av = *(const float4*)&As[kk][r0];
      float4 bv = *(const float4*)&Ws[kk][c0];
      const f32x2 b0 = {bv.x, bv.y}, b1 = {bv.z, bv.w};
      float ar[4] = {av.x, av.y, av.z, av.w};
#pragma unroll
      for (int i = 0; i < 4; i++) {
        f32x2 ai = {ar[i], ar[i]};
        acc[i][0] = pkfma(b0, ai, acc[i][0]);
        acc[i][1] = pkfma(b1, ai, acc[i][1]);
      }
    }
  }
#pragma unroll
  for (int i = 0; i < 4; i++) {
    int row = m0 + r0 + i;
#pragma unroll
    for (int j = 0; j < 4; j++) {
      int col = n0 + c0 + j;
      if (col < N) {
        float v = acc[i][j >> 1][j & 1] + bias[col];
        C[(size_t)row * N + col] = RELU ? fmaxf(v, 0.f) : v;
      }
    }
  }
}

// ---- upconv1: upsample 21->42 + residual 3x3 conv + relu.
//      Fill: one thread per tile position (coefficients computed ONCE),
//      channel loop with pointer increments.  Conv: 12 packed-f32 pairs,
//      weights wave-uniform -> SGPR.  LDS 33 KB, 4 blocks/CU. ----
__global__ __launch_bounds__(256, 4) void upconv1_k(
    const float* __restrict__ X, const float* __restrict__ wt,
    const float* __restrict__ bias, float* __restrict__ out) {
  constexpr int S_IN = 21, S_OUT = 42, TR = 6, UH = 8, UW = 44, NTILE = 7;
  __shared__ __align__(16) float sU[24 * UH * UW];   // 8448 floats = 33 KB
  const int b = blockIdx.x / NTILE;
  const int y0 = (blockIdx.x % NTILE) * TR;
  const int t = threadIdx.x;
  const float* xb = X + (size_t)b * 24 * S_IN * S_IN;
  const float sc = (float)(S_IN - 1) / (float)(S_OUT - 1);
  // positions rr = t and t+256 (tile has 8*44=352 positions)
  for (int rr = t; rr < UH * UW; rr += 256) {
    const int ry = rr / UW, cx = rr % UW;
    const int y = y0 + ry - 1, x = cx - 1;
    float* sdst = &sU[rr];
    if (y >= 0 && y < S_OUT && x >= 0 && x < S_OUT) {
      float py = y * sc, px = x * sc;
      int ly = (int)py; if (ly > S_IN - 2) ly = S_IN - 2;
      int lx = (int)px; if (lx > S_IN - 2) lx = S_IN - 2;
      float wy = py - (float)ly, wx = px - (float)lx;
      const f32x2 wxv = {wx, wx};
      const float* xc = xb + ly * S_IN + lx;
      for (int c = 0; c < 24; c++) {
        f32x2 a  = {xc[0], xc[S_IN]};        // {v00, v10}
        f32x2 bb = {xc[1], xc[S_IN + 1]};    // {v01, v11}
        f32x2 h = pkfma(wxv, bb - a, a);     // {h_top, h_bot}
        *sdst = h[0] + wy * (h[1] - h[0]);
        xc += S_IN * S_IN;
        sdst += UH * UW;
      }
    } else {
      for (int c = 0; c < 24; c++) { *sdst = 0.f; sdst += UH * UW; }
    }
  }
  __syncthreads();
  if (t < 252) {
    const int ry = t / 42, lx = t % 42;
    f32x2 acc[12];
#pragma unroll
    for (int j = 0; j < 12; j++) acc[j] = f32x2{0.f, 0.f};
    for (int ic = 0; ic < 24; ic++) {
      const float* urow = &sU[(ic * UH + ry) * UW + lx];
      const float* wp = wt + ic * 216;   // [3][3][24], uniform -> s_load
#pragma unroll
      for (int ky = 0; ky < 3; ky++) {
        float x0v = urow[ky * UW + 0];
        float x1v = urow[ky * UW + 1];
        float x2v = urow[ky * UW + 2];
        f32x2 X0 = {x0v, x0v}, X1 = {x1v, x1v}, X2 = {x2v, x2v};
        const f32x2* wk2 = (const f32x2*)(wp + ky * 72);
#pragma unroll
        for (int j = 0; j < 12; j++)
          acc[j] = pkfma(wk2[j], X0,
                   pkfma(wk2[12 + j], X1,
                   pkfma(wk2[24 + j], X2, acc[j])));
      }
    }
    const int yy = y0 + ry;
#pragma unroll
    for (int j = 0; j < 12; j++) {
      f32x2 u2 = { sU[((2*j)   * UH + ry + 1) * UW + lx + 1],
                   sU[((2*j+1) * UH + ry + 1) * UW + lx + 1] };
      f32x2 b2 = *(const f32x2*)&bias[2*j];
      f32x2 s = u2 + acc[j] + b2;
      out[(((size_t)b * 24 + 2*j    ) * S_OUT + yy) * S_OUT + lx] = fmaxf(s[0], 0.f);
      out[(((size_t)b * 24 + 2*j + 1) * S_OUT + yy) * S_OUT + lx] = fmaxf(s[1], 0.f);
    }
  }
}

// ---- fused: upsample 42->84 + residual conv + relu + 1x1 conv + sigmoid
//      + flow + bilinear warp.  Fill restructured as in upconv1; 24 channels
//      as 12 packed-f32 pairs; head params uniform -> SGPR.  LDS 33 KB. ----
__global__ __launch_bounds__(256, 4) void upconv2_final_k(
    const float* __restrict__ R1, const float* __restrict__ inp,
    const float* __restrict__ wt, const float* __restrict__ bias,
    const float* __restrict__ c3w, const float* __restrict__ c3b,
    const float* __restrict__ ot, const float* __restrict__ ct,
    float* __restrict__ out) {
  constexpr int S_IN = 42, S_OUT = 84, TR = 6, UH = 8, TW = 42, UW = 44;
  __shared__ __align__(16) float sU[24 * UH * UW];   // 8448 floats = 33 KB
  const int blk = blockIdx.x;
  const int b = blk / 28;
  const int rr0 = blk % 28;
  const int y0 = (rr0 >> 1) * TR;
  const int x0 = (rr0 & 1) * TW;
  const int t = threadIdx.x;
  const float* xb = R1 + (size_t)b * 24 * S_IN * S_IN;
  const float sc = (float)(S_IN - 1) / (float)(S_OUT - 1);
  for (int rr = t; rr < UH * UW; rr += 256) {
    const int ry = rr / UW, cx = rr % UW;
    const int y = y0 + ry - 1, x = x0 + cx - 1;
    float* sdst = &sU[rr];
    if (y >= 0 && y < S_OUT && x >= 0 && x < S_OUT) {
      float py = y * sc, px = x * sc;
      int ly = (int)py; if (ly > S_IN - 2) ly = S_IN - 2;
      int lx = (int)px; if (lx > S_IN - 2) lx = S_IN - 2;
      float wy = py - (float)ly, wx = px - (float)lx;
      const f32x2 wxv = {wx, wx};
      const float* xc = xb + ly * S_IN + lx;
      for (int c = 0; c < 24; c++) {
        f32x2 a  = {xc[0], xc[S_IN]};
        f32x2 bb = {xc[1], xc[S_IN + 1]};
        f32x2 h = pkfma(wxv, bb - a, a);
        *sdst = h[0] + wy * (h[1] - h[0]);
        xc += S_IN * S_IN;
        sdst += UH * UW;
      }
    } else {
      for (int c = 0; c < 24; c++) { *sdst = 0.f; sdst += UH * UW; }
    }
  }
  __syncthreads();
  if (t < 252) {
    const int ry = t / 42, lx = t % 42;
    f32x2 acc[12];
#pragma unroll
    for (int j = 0; j < 12; j++) acc[j] = f32x2{0.f, 0.f};
    for (int ic = 0; ic < 24; ic++) {
      const float* urow = &sU[(ic * UH + ry) * UW + lx];
      const float* wp = wt + ic * 216;   // uniform -> s_load
#pragma unroll
      for (int ky = 0; ky < 3; ky++) {
        float x0v = urow[ky * UW + 0];
        float x1v = urow[ky * UW + 1];
        float x2v = urow[ky * UW + 2];
        f32x2 X0 = {x0v, x0v}, X1 = {x1v, x1v}, X2 = {x2v, x2v};
        const f32x2* wk2 = (const f32x2*)(wp + ky * 72);
#pragma unroll
        for (int j = 0; j < 12; j++)
          acc[j] = pkfma(wk2[j], X0,
                   pkfma(wk2[12 + j], X1,
                   pkfma(wk2[24 + j], X2, acc[j])));
      }
    }
    // residual + relu, kept in register pairs
    f32x2 r[12];
#pragma unroll
    for (int j = 0; j < 12; j++) {
      f32x2 u2 = { sU[((2*j)   * UH + ry + 1) * UW + lx + 1],
                   sU[((2*j+1) * UH + ry + 1) * UW + lx + 1] };
      f32x2 b2 = *(const f32x2*)&bias[2*j];
      f32x2 s = u2 + acc[j] + b2;
      r[j][0] = fmaxf(s[0], 0.f);
      r[j][1] = fmaxf(s[1], 0.f);
    }
    // 1x1 conv + sigmoid + flow accumulation (head params uniform -> SGPR)
    f32x2 f2 = *(const f32x2*)&ct[b * 2];            // {fy, fx}
    const f32x2* ot2 = (const f32x2*)(ot + b * 2 * KOBJ);
    for (int k = 0; k < KOBJ; k++) {
      f32x2 zv = {c3b[k], 0.f};
      const f32x2* cw2 = (const f32x2*)(c3w + k * 24);
#pragma unroll
      for (int j = 0; j < 12; j++) zv = pkfma(r[j], cw2[j], zv);
      float z = zv[0] + zv[1];
      float m = 1.f / (1.f + __expf(-z));
      f32x2 mv = {m, m};
      f2 = pkfma(mv, ot2[k], f2);
    }
    const int gy = y0 + ry, gx = x0 + lx;
    const float imgf = 0.01f * 84.0f;
    float ys = imgf * f2[0] + (float)gy;
    float xs = imgf * f2[1] + (float)gx;
    int ix0 = (int)floorf(xs); ix0 = ix0 < 0 ? 0 : (ix0 > 83 ? 83 : ix0);
    int iy0 = (int)floorf(ys); iy0 = iy0 < 0 ? 0 : (iy0 > 83 ? 83 : iy0);
    int ix1 = ix0 + 1 > 83 ? 83 : ix0 + 1;
    int iy1 = iy0 + 1 > 83 ? 83 : iy0 + 1;
    float xc = fminf(fmaxf(xs, 0.f), 83.f);
    float yc = fminf(fmaxf(ys, 0.f), 83.f);
    float wx1 = (float)ix1 - xc, wx0 = xc - (float)ix0;
    float wy1 = (float)iy1 - yc, wy0 = yc - (float)iy0;
    const float* src = inp + ((size_t)b * 2 + 1) * NPIX;
    float Ia = src[iy0 * 84 + ix0], Ib = src[iy1 * 84 + ix0];
    float Ic = src[iy0 * 84 + ix1], Id = src[iy1 * 84 + ix1];
    out[(size_t)b * NPIX + gy * 84 + gx] =
        wx1 * wy1 * Ia + wx1 * wy0 * Ib + wx0 * wy1 * Ic + wx0 * wy0 * Id;
  }
}

}  // namespace

extern "C" void kernel_launch(void* const* d_in, const int* in_sizes, int n_in,
                              void* d_out, int out_size, void* d_ws, size_t ws_size,
                              hipStream_t stream) {
  const float* inp = (const float*)d_in[0];
  const float* cw1 = (const float*)d_in[1];
  const float* cb1 = (const float*)d_in[2];
  const float* cw2 = (const float*)d_in[3];
  const float* cb2 = (const float*)d_in[4];
  const float* cw3 = (const float*)d_in[5];
  const float* cb3 = (const float*)d_in[6];
  const float* fcw = (const float*)d_in[7];
  const float* fcb = (const float*)d_in[8];
  const float* otw = (const float*)d_in[9];
  const float* otb = (const float*)d_in[10];
  const float* ctw = (const float*)d_in[11];
  const float* ctb = (const float*)d_in[12];
  const float* m1w = (const float*)d_in[13];
  const float* m1b = (const float*)d_in[14];
  const float* c1w = (const float*)d_in[15];
  const float* c1b = (const float*)d_in[16];
  const float* c2w = (const float*)d_in[17];
  const float* c2b = (const float*)d_in[18];
  const float* c3w = (const float*)d_in[19];
  const float* c3b = (const float*)d_in[20];
  float* W = (float*)d_ws;
  float* out = (float*)d_out;

  transpose_w<<<(64 * 512 + 255) / 256, 256, 0, stream>>>(cw2, W + OFF_WT2, 64, 512);
  transpose_w<<<(64 * 576 + 255) / 256, 256, 0, stream>>>(cw3, W + OFF_WT3, 64, 576);
  conv1_k<<<512, 256, 0, stream>>>(inp, cw1, cb1, W + OFF_H1);
  conv2_k<<<512, 256, 0, stream>>>(W + OFF_H1, W + OFF_WT2, cb2, W + OFF_H2);
  conv3_k<<<512, 256, 0, stream>>>(W + OFF_H2, W + OFF_WT3, cb3, W + OFF_FEAT);
  // decoder conv weight transposes (WT2/WT3 slots are dead now):
  // [24][24][3][3] -> [ic*9+ky*3+kx][oc]
  transpose_w<<<(24 * 216 + 255) / 256, 256, 0, stream>>>(c1w, W + OFF_WT2, 24, 216);
  transpose_w<<<(24 * 216 + 255) / 256, 256, 0, stream>>>(c2w, W + OFF_WT3, 24, 216);
  // x = relu(feat @ fcw^T + fcb)
  gemm_k<true><<<dim3(8, 8), 256, 0, stream>>>(W + OFF_FEAT, fcw, fcb, W + OFF_X, 512, 3136);
  // heads
  gemm_k<false><<<dim3(1, 8), 256, 0, stream>>>(W + OFF_X, otw, otb, W + OFF_OT, 40, 512);
  gemm_k<false><<<dim3(1, 8), 256, 0, stream>>>(W + OFF_X, ctw, ctb, W + OFF_CT, 2, 512);
  // m0 = x @ m1w^T + m1b   [512, 10584]
  gemm_k<false><<<dim3(166, 8), 256, 0, stream>>>(W + OFF_X, m1w, m1b, W + OFF_M0, 10584, 512);
  // decoder
  upconv1_k<<<512 * 7, 256, 0, stream>>>(W + OFF_M0, W + OFF_WT2, c1b, W + OFF_R1);
  upconv2_final_k<<<512 * 28, 256, 0, stream>>>(W + OFF_R1, inp, W + OFF_WT3, c2b,
                                                c3w, c3b, W + OFF_OT, W + OFF_CT, out);
}